// Round 3
// baseline (807.167 us; speedup 1.0000x reference)
//
#include <hip/hip_runtime.h>
#include <math.h>

// Problem constants (fixed by reference)
#define BB   2
#define TT   4096            // tokens per batch
#define NT   (BB*TT)         // 8192 total rows
#define DD   1024
#define CQ   128             // k_query dim
#define TK   8               // top_k
#define NCH  16              // s-chunks for sim kernel
#define SC   (TT/NCH)        // 256 s per chunk

// ---------------------------------------------------------------------------
// top-8 sorted insert, STRICT comparator. Correct vs jax.lax.top_k tie rules
// as long as candidates are inserted in ascending index order (strict '>'
// keeps the earlier index on equal values, which is lax.top_k's tie-break).
// ---------------------------------------------------------------------------
__device__ __forceinline__ void topk8_insert_strict(float (&v)[TK], int (&ix)[TK],
                                                    float val, int idx) {
    float cv = val; int ci = idx;
#pragma unroll
    for (int i = 0; i < TK; ++i) {
        bool sw = (cv > v[i]);
        float tv = v[i]; int ti = ix[i];
        v[i]  = sw ? cv : tv;  ix[i] = sw ? ci : ti;
        cv    = sw ? tv : cv;  ci    = sw ? ti : ci;
    }
}

// tie-break-aware insert (used in merge where cross-chunk order is mixed)
__device__ __forceinline__ void topk8_insert(float (&v)[TK], int (&ix)[TK],
                                             float val, int idx) {
    float cv = val; int ci = idx;
#pragma unroll
    for (int i = 0; i < TK; ++i) {
        bool sw = (cv > v[i]) || (cv == v[i] && ci < ix[i]);
        float tv = v[i]; int ti = ix[i];
        v[i]  = sw ? cv : tv;  ix[i] = sw ? ci : ti;
        cv    = sw ? tv : cv;  ci    = sw ? ti : ci;
    }
}

// ---------------------------------------------------------------------------
// K1: q = x@Wq + bq ; k = x@Wk + bk   (f32, W broadcast via uniform loads)
// ---------------------------------------------------------------------------
__global__ __launch_bounds__(256) void proj_kernel(
    const float* __restrict__ x,
    const float* __restrict__ Wq, const float* __restrict__ bq,
    const float* __restrict__ Wk, const float* __restrict__ bk,
    float* __restrict__ q, float* __restrict__ k)
{
    int row = blockIdx.x * 256 + threadIdx.x;        // 0..NT-1
    int cc  = blockIdx.y * 16;                       // combined col 0..255
    bool isK = cc >= CQ;
    const float* W    = isK ? Wk : Wq;
    const float* bias = isK ? bk : bq;
    int c0 = isK ? cc - CQ : cc;

    float acc[16];
#pragma unroll
    for (int j = 0; j < 16; ++j) acc[j] = 0.f;

    const float* xr = x + (size_t)row * DD;
    for (int d0 = 0; d0 < DD; d0 += 4) {
        float4 xv = *reinterpret_cast<const float4*>(xr + d0);
        const float* w0 = W + (size_t)d0 * CQ + c0;
#pragma unroll
        for (int j = 0; j < 16; ++j) {
            acc[j] = fmaf(xv.x, w0[j],        acc[j]);
            acc[j] = fmaf(xv.y, w0[CQ + j],   acc[j]);
            acc[j] = fmaf(xv.z, w0[2*CQ + j], acc[j]);
            acc[j] = fmaf(xv.w, w0[3*CQ + j], acc[j]);
        }
    }
    float* outp = (isK ? k : q) + (size_t)row * CQ + c0;
#pragma unroll
    for (int j = 0; j < 16; ++j) outp[j] = acc[j] + bias[c0 + j];
}

// ---------------------------------------------------------------------------
// K1b: gates = sigmoid(x@Wg + bg)   one wave per row
// ---------------------------------------------------------------------------
__global__ __launch_bounds__(256) void gate_kernel(
    const float* __restrict__ x, const float* __restrict__ Wg,
    const float* __restrict__ bg, float* __restrict__ gout)
{
    int wave = threadIdx.x >> 6, lane = threadIdx.x & 63;
    int row  = blockIdx.x * 4 + wave;
    const float* xr = x + (size_t)row * DD;
    float s = 0.f;
#pragma unroll
    for (int i = 0; i < 4; ++i) {
        int d = (i * 64 + lane) * 4;
        float4 xv = *reinterpret_cast<const float4*>(xr + d);
        float4 wv = *reinterpret_cast<const float4*>(Wg + d);
        s = fmaf(xv.x, wv.x, s); s = fmaf(xv.y, wv.y, s);
        s = fmaf(xv.z, wv.z, s); s = fmaf(xv.w, wv.w, s);
    }
#pragma unroll
    for (int off = 32; off; off >>= 1) s += __shfl_xor(s, off);
    if (lane == 0) gout[row] = 1.f / (1.f + expf(-(s + bg[0])));
}

// ---------------------------------------------------------------------------
// K2: sim + partial top-8.
// Layout: 1 lane = 1 full query. q row (128 f32) lives in VGPRs.
// k row for step si is WAVE-UNIFORM -> broadcast loads (compiler may
// scalarize to s_load since the address is uniform & __restrict__ const).
// Per si per wave: 128 useful FMAs; insert amortized over 64 queries.
// ---------------------------------------------------------------------------
__global__ __launch_bounds__(256, 2) void simtopk_kernel(
    const float* __restrict__ q, const float* __restrict__ kmat,
    const float* __restrict__ gates, const float* __restrict__ am,
    float* __restrict__ pv, int* __restrict__ pi)
{
    int wave = threadIdx.x >> 6;
    int lane = threadIdx.x & 63;
    int qg   = blockIdx.x * 4 + wave;          // query group 0..127
    int t    = qg * 64 + lane;                  // global query 0..NT-1
    int ch   = blockIdx.y;
    int b    = t >> 12;                         // batch, wave-uniform (64|4096)
    int s0   = ch * SC;

    // full q row: 32 float4 = 128 VGPRs
    float4 qv[32];
    const float4* qp = reinterpret_cast<const float4*>(q + (size_t)t * CQ);
#pragma unroll
    for (int m = 0; m < 32; ++m) qv[m] = qp[m];

    float gate = gates[t];
    float mq   = am[t];
    const float scale = 0.08838834764831845f;  // 1/sqrt(128)
    float sg = scale * gate;
    float mneg = -1e9f * gate;

    float v[TK]; int ix[TK];
#pragma unroll
    for (int j = 0; j < TK; ++j) { v[j] = -3.0e38f; ix[j] = 0; }

    const float* kbase = kmat + ((size_t)(b * TT + s0)) * CQ;
    const float* amb   = am + b * TT + s0;

    for (int si = 0; si < SC; ++si) {
        const float4* kr = reinterpret_cast<const float4*>(kbase + (size_t)si * CQ);
        float a0 = 0.f, a1 = 0.f, a2 = 0.f, a3 = 0.f;
        // 4 sub-chunks of 8 float4; fully unrolled -> SSA, no reg copies,
        // bounded liveness (~2 sub-chunks of k in flight).
#pragma unroll
        for (int c = 0; c < 4; ++c) {
            float4 k0 = kr[c * 8 + 0], k1 = kr[c * 8 + 1];
            float4 k2 = kr[c * 8 + 2], k3 = kr[c * 8 + 3];
            float4 k4 = kr[c * 8 + 4], k5 = kr[c * 8 + 5];
            float4 k6 = kr[c * 8 + 6], k7 = kr[c * 8 + 7];
            const float4* qc = &qv[c * 8];
            a0 = fmaf(qc[0].x, k0.x, a0); a1 = fmaf(qc[0].y, k0.y, a1);
            a2 = fmaf(qc[0].z, k0.z, a2); a3 = fmaf(qc[0].w, k0.w, a3);
            a0 = fmaf(qc[1].x, k1.x, a0); a1 = fmaf(qc[1].y, k1.y, a1);
            a2 = fmaf(qc[1].z, k1.z, a2); a3 = fmaf(qc[1].w, k1.w, a3);
            a0 = fmaf(qc[2].x, k2.x, a0); a1 = fmaf(qc[2].y, k2.y, a1);
            a2 = fmaf(qc[2].z, k2.z, a2); a3 = fmaf(qc[2].w, k2.w, a3);
            a0 = fmaf(qc[3].x, k3.x, a0); a1 = fmaf(qc[3].y, k3.y, a1);
            a2 = fmaf(qc[3].z, k3.z, a2); a3 = fmaf(qc[3].w, k3.w, a3);
            a0 = fmaf(qc[4].x, k4.x, a0); a1 = fmaf(qc[4].y, k4.y, a1);
            a2 = fmaf(qc[4].z, k4.z, a2); a3 = fmaf(qc[4].w, k4.w, a3);
            a0 = fmaf(qc[5].x, k5.x, a0); a1 = fmaf(qc[5].y, k5.y, a1);
            a2 = fmaf(qc[5].z, k5.z, a2); a3 = fmaf(qc[5].w, k5.w, a3);
            a0 = fmaf(qc[6].x, k6.x, a0); a1 = fmaf(qc[6].y, k6.y, a1);
            a2 = fmaf(qc[6].z, k6.z, a2); a3 = fmaf(qc[6].w, k6.w, a3);
            a0 = fmaf(qc[7].x, k7.x, a0); a1 = fmaf(qc[7].y, k7.y, a1);
            a2 = fmaf(qc[7].z, k7.z, a2); a3 = fmaf(qc[7].w, k7.w, a3);
        }
        float dot = (a0 + a1) + (a2 + a3);

        int s = s0 + si;
        float ms = amb[si];                     // uniform scalar
        float val = (mq * ms == 0.f) ? mneg : dot * sg;
        if (val > v[TK - 1])
            topk8_insert_strict(v, ix, val, s);
    }

    int base = (t * NCH + ch) * TK;
#pragma unroll
    for (int j = 0; j < TK; ++j) { pv[base + j] = v[j]; pi[base + j] = ix[j]; }
}

// ---------------------------------------------------------------------------
// K3: merge NCH partial top-8 lists -> final top-8; write idx (as float),
// values, and gather x rows. block per query, 256 threads.
// ---------------------------------------------------------------------------
__global__ __launch_bounds__(256) void merge_gather_kernel(
    const float* __restrict__ x,
    const float* __restrict__ pv, const int* __restrict__ pi,
    float* __restrict__ out_g, float* __restrict__ out_i,
    float* __restrict__ out_v)
{
    int t = blockIdx.x;
    __shared__ int sidx[TK];

    if (threadIdx.x == 0) {
        float v[TK]; int ix[TK];
#pragma unroll
        for (int j = 0; j < TK; ++j) { v[j] = -3.0e38f; ix[j] = 0; }
        const float* pvb = pv + (size_t)t * NCH * TK;
        const int*   pib = pi + (size_t)t * NCH * TK;
        for (int c = 0; c < NCH * TK; ++c) {
            float val = pvb[c]; int s = pib[c];
            if (val > v[TK-1] || (val == v[TK-1] && s < ix[TK-1]))
                topk8_insert(v, ix, val, s);
        }
#pragma unroll
        for (int j = 0; j < TK; ++j) {
            out_i[t * TK + j] = (float)ix[j];
            out_v[t * TK + j] = v[j];
            sidx[j] = ix[j];
        }
    }
    __syncthreads();

    int b = t >> 12;
#pragma unroll
    for (int j = 0; j < TK; ++j) {
        int row = sidx[j];
        float4 val = *reinterpret_cast<const float4*>(
            x + ((size_t)(b * TT + row)) * DD + threadIdx.x * 4);
        *reinterpret_cast<float4*>(
            out_g + ((size_t)(t * TK + j)) * DD + threadIdx.x * 4) = val;
    }
}

// ---------------------------------------------------------------------------
extern "C" void kernel_launch(void* const* d_in, const int* in_sizes, int n_in,
                              void* d_out, int out_size, void* d_ws, size_t ws_size,
                              hipStream_t stream) {
    const float* x  = (const float*)d_in[0];
    const float* am = (const float*)d_in[1];
    const float* Wq = (const float*)d_in[2];
    const float* bq = (const float*)d_in[3];
    const float* Wk = (const float*)d_in[4];
    const float* bk = (const float*)d_in[5];
    const float* Wg = (const float*)d_in[6];
    const float* bg = (const float*)d_in[7];

    float* ws = (float*)d_ws;
    float* q  = ws;                              // NT*CQ      = 1048576
    float* k  = ws + 1048576;                    // NT*CQ      = 1048576
    float* g  = ws + 2097152;                    // NT         = 8192
    float* pv = ws + 2105344;                    // NT*NCH*TK  = 1048576
    int*   pi = (int*)(ws + 3153920);            // NT*NCH*TK  = 1048576

    float* out_g = (float*)d_out;                // [B,T,K,D] = 67108864
    float* out_i = out_g + 67108864;             // [B,T,K]   = 65536 (as float)
    float* out_v = out_i + 65536;                // [B,T,K]   = 65536

    proj_kernel<<<dim3(NT / 256, 16), 256, 0, stream>>>(x, Wq, bq, Wk, bk, q, k);
    gate_kernel<<<NT / 4, 256, 0, stream>>>(x, Wg, bg, g);
    simtopk_kernel<<<dim3(32, NCH), 256, 0, stream>>>(q, k, g, am, pv, pi);
    merge_gather_kernel<<<NT, 256, 0, stream>>>(x, pv, pi, out_g, out_i, out_v);
}

// Round 5
// 501.273 us; speedup vs baseline: 1.6102x; 1.6102x over previous
//
#include <hip/hip_runtime.h>
#include <math.h>

// Problem constants (fixed by reference)
#define BB   2
#define TT   4096            // tokens per batch
#define NT   (BB*TT)         // 8192 total rows
#define DD   1024
#define CQ   128             // k_query dim
#define TK   8               // top_k
#define NCH  16              // s-splits (partial top-8 lists per query)

// ---------------------------------------------------------------------------
// top-8 sorted insert, STRICT comparator: correct vs jax.lax.top_k tie rules
// when candidates arrive in ascending index order.
// ---------------------------------------------------------------------------
__device__ __forceinline__ void topk8_insert_strict(float (&v)[TK], int (&ix)[TK],
                                                    float val, int idx) {
    float cv = val; int ci = idx;
#pragma unroll
    for (int i = 0; i < TK; ++i) {
        bool sw = (cv > v[i]);
        float tv = v[i]; int ti = ix[i];
        v[i]  = sw ? cv : tv;  ix[i] = sw ? ci : ti;
        cv    = sw ? tv : cv;  ci    = sw ? ti : ci;
    }
}

// tie-break-aware insert (for merging lists whose index order is mixed)
__device__ __forceinline__ void topk8_insert(float (&v)[TK], int (&ix)[TK],
                                             float val, int idx) {
    float cv = val; int ci = idx;
#pragma unroll
    for (int i = 0; i < TK; ++i) {
        bool sw = (cv > v[i]) || (cv == v[i] && ci < ix[i]);
        float tv = v[i]; int ti = ix[i];
        v[i]  = sw ? cv : tv;  ix[i] = sw ? ci : ti;
        cv    = sw ? tv : cv;  ci    = sw ? ti : ci;
    }
}

// f64 tie-break-aware insert (final exact ranking)
__device__ __forceinline__ void topk8d_insert(double (&v)[TK], int (&ix)[TK],
                                              double val, int idx) {
    double cv = val; int ci = idx;
#pragma unroll
    for (int i = 0; i < TK; ++i) {
        bool sw = (cv > v[i]) || (cv == v[i] && ci < ix[i]);
        double tv = v[i]; int ti = ix[i];
        v[i]  = sw ? cv : tv;  ix[i] = sw ? ci : ti;
        cv    = sw ? tv : cv;  ci    = sw ? ti : ci;
    }
}

// ---------------------------------------------------------------------------
// K1: q = x@Wq + bq ; k = x@Wk + bk   (f32, W broadcast via uniform loads)
// ---------------------------------------------------------------------------
__global__ __launch_bounds__(256) void proj_kernel(
    const float* __restrict__ x,
    const float* __restrict__ Wq, const float* __restrict__ bq,
    const float* __restrict__ Wk, const float* __restrict__ bk,
    float* __restrict__ q, float* __restrict__ k)
{
    int row = blockIdx.x * 256 + threadIdx.x;        // 0..NT-1
    int cc  = blockIdx.y * 16;                       // combined col 0..255
    bool isK = cc >= CQ;
    const float* W    = isK ? Wk : Wq;
    const float* bias = isK ? bk : bq;
    int c0 = isK ? cc - CQ : cc;

    float acc[16];
#pragma unroll
    for (int j = 0; j < 16; ++j) acc[j] = 0.f;

    const float* xr = x + (size_t)row * DD;
    for (int d0 = 0; d0 < DD; d0 += 4) {
        float4 xv = *reinterpret_cast<const float4*>(xr + d0);
        const float* w0 = W + (size_t)d0 * CQ + c0;
#pragma unroll
        for (int j = 0; j < 16; ++j) {
            acc[j] = fmaf(xv.x, w0[j],        acc[j]);
            acc[j] = fmaf(xv.y, w0[CQ + j],   acc[j]);
            acc[j] = fmaf(xv.z, w0[2*CQ + j], acc[j]);
            acc[j] = fmaf(xv.w, w0[3*CQ + j], acc[j]);
        }
    }
    float* outp = (isK ? k : q) + (size_t)row * CQ + c0;
#pragma unroll
    for (int j = 0; j < 16; ++j) outp[j] = acc[j] + bias[c0 + j];
}

// ---------------------------------------------------------------------------
// K1b: gates = sigmoid(x@Wg + bg)   one wave per row
// ---------------------------------------------------------------------------
__global__ __launch_bounds__(256) void gate_kernel(
    const float* __restrict__ x, const float* __restrict__ Wg,
    const float* __restrict__ bg, float* __restrict__ gout)
{
    int wave = threadIdx.x >> 6, lane = threadIdx.x & 63;
    int row  = blockIdx.x * 4 + wave;
    const float* xr = x + (size_t)row * DD;
    float s = 0.f;
#pragma unroll
    for (int i = 0; i < 4; ++i) {
        int d = (i * 64 + lane) * 4;
        float4 xv = *reinterpret_cast<const float4*>(xr + d);
        float4 wv = *reinterpret_cast<const float4*>(Wg + d);
        s = fmaf(xv.x, wv.x, s); s = fmaf(xv.y, wv.y, s);
        s = fmaf(xv.z, wv.z, s); s = fmaf(xv.w, wv.w, s);
    }
#pragma unroll
    for (int off = 32; off; off >>= 1) s += __shfl_xor(s, off);
    if (lane == 0) gout[row] = 1.f / (1.f + expf(-(s + bg[0])));
}

// ---------------------------------------------------------------------------
// K2: tiled f32 GEMM (64q x 64s per chunk, K=128 resident in LDS) + decoupled
// top-8 scan of the LDS sim tile. Grid (128 q-tiles, 16 s-splits); each block
// processes 4 chunks of 64 keys (256 keys), keeping running top-8 in regs.
// This kernel only GENERATES CANDIDATES; exact ranking happens in K3 (f64).
// ---------------------------------------------------------------------------
__global__ __launch_bounds__(256, 2) void simtopk_kernel(
    const float* __restrict__ q, const float* __restrict__ kmat,
    const float* __restrict__ gates, const float* __restrict__ am,
    float* __restrict__ pv, int* __restrict__ pi)
{
    __shared__ float Alds[8192];   // 32 KB: q-tile, transposed+swizzled
    __shared__ float Blds[8192];   // 32 KB: k-chunk tile; reused as sim buffer

    const int tid = threadIdx.x;
    const int ty  = tid >> 4;          // 0..15 -> queries ty*4..+3
    const int tx  = tid & 15;          // 0..15 -> keys    tx*4..+3
    const int qt  = blockIdx.x;        // 0..127
    const int sp  = blockIdx.y;        // 0..15
    const int t0  = qt * 64;
    const int b   = t0 >> 12;          // batch

    // staging role
    const int c4 = tid & 31;           // float4-column within the 128-dim
    const int rr0 = tid >> 5;          // 0..7

    // scan role: 4 threads per query, 16 keys each per chunk
    const int scanq = tid >> 2;        // 0..63
    const int vsl   = tid & 3;         // slice
    const int tq    = t0 + scanq;      // global query
    const float gate = gates[tq];
    const float mq   = am[tq];
    const float sgq  = 0.08838834764831845f * gate;   // scale * gate
    const float mneg = -1e9f * gate;

    float tv[TK]; int tix[TK];
#pragma unroll
    for (int j = 0; j < TK; ++j) { tv[j] = -3.0e38f; tix[j] = 0; }

    // ---- stage A (q rows t0..t0+63) once ----
#pragma unroll
    for (int pass = 0; pass < 8; ++pass) {
        int ql = rr0 + pass * 8;
        float4 g4 = *reinterpret_cast<const float4*>(
            q + (size_t)(t0 + ql) * CQ + c4 * 4);
        int col = (((ql >> 2) ^ (c4 & 15)) << 2) + (ql & 3);
        Alds[(c4 * 4 + 0) * 64 + col] = g4.x;
        Alds[(c4 * 4 + 1) * 64 + col] = g4.y;
        Alds[(c4 * 4 + 2) * 64 + col] = g4.z;
        Alds[(c4 * 4 + 3) * 64 + col] = g4.w;
    }

    float4 breg[8];
    // load B chunk 0
#pragma unroll
    for (int pass = 0; pass < 8; ++pass) {
        int sl = rr0 + pass * 8;
        breg[pass] = *reinterpret_cast<const float4*>(
            kmat + (size_t)(b * TT + sp * 256 + sl) * CQ + c4 * 4);
    }
#pragma unroll
    for (int pass = 0; pass < 8; ++pass) {
        int sl = rr0 + pass * 8;
        int col = (((sl >> 2) ^ (c4 & 15)) << 2) + (sl & 3);
        Blds[(c4 * 4 + 0) * 64 + col] = breg[pass].x;
        Blds[(c4 * 4 + 1) * 64 + col] = breg[pass].y;
        Blds[(c4 * 4 + 2) * 64 + col] = breg[pass].z;
        Blds[(c4 * 4 + 3) * 64 + col] = breg[pass].w;
    }
    __syncthreads();

    for (int ck = 0; ck < 4; ++ck) {
        // ---- GEMM: 64x64 tile, K=128 ----
        float acc[4][4] = {{0.f,0.f,0.f,0.f},{0.f,0.f,0.f,0.f},
                           {0.f,0.f,0.f,0.f},{0.f,0.f,0.f,0.f}};
#pragma unroll 4
        for (int k4 = 0; k4 < 32; ++k4) {
            int mask = k4 & 15;
            const float* Ab = &Alds[k4 * 256 + ((ty ^ mask) << 2)];
            const float* Bb = &Blds[k4 * 256 + ((tx ^ mask) << 2)];
#pragma unroll
            for (int r = 0; r < 4; ++r) {
                float4 a4 = *reinterpret_cast<const float4*>(Ab + r * 64);
                float4 b4 = *reinterpret_cast<const float4*>(Bb + r * 64);
                acc[0][0] = fmaf(a4.x, b4.x, acc[0][0]);
                acc[0][1] = fmaf(a4.x, b4.y, acc[0][1]);
                acc[0][2] = fmaf(a4.x, b4.z, acc[0][2]);
                acc[0][3] = fmaf(a4.x, b4.w, acc[0][3]);
                acc[1][0] = fmaf(a4.y, b4.x, acc[1][0]);
                acc[1][1] = fmaf(a4.y, b4.y, acc[1][1]);
                acc[1][2] = fmaf(a4.y, b4.z, acc[1][2]);
                acc[1][3] = fmaf(a4.y, b4.w, acc[1][3]);
                acc[2][0] = fmaf(a4.z, b4.x, acc[2][0]);
                acc[2][1] = fmaf(a4.z, b4.y, acc[2][1]);
                acc[2][2] = fmaf(a4.z, b4.z, acc[2][2]);
                acc[2][3] = fmaf(a4.z, b4.w, acc[2][3]);
                acc[3][0] = fmaf(a4.w, b4.x, acc[3][0]);
                acc[3][1] = fmaf(a4.w, b4.y, acc[3][1]);
                acc[3][2] = fmaf(a4.w, b4.z, acc[3][2]);
                acc[3][3] = fmaf(a4.w, b4.w, acc[3][3]);
            }
        }
        __syncthreads();   // all GEMM reads of Blds done

        // issue next chunk's B loads early (latency hides under simwrite+scan)
        if (ck < 3) {
#pragma unroll
            for (int pass = 0; pass < 8; ++pass) {
                int sl = rr0 + pass * 8;
                breg[pass] = *reinterpret_cast<const float4*>(
                    kmat + (size_t)(b * TT + sp * 256 + (ck + 1) * 64 + sl) * CQ
                         + c4 * 4);
            }
        }

        // ---- write sim tile into Blds as [64 q][stride 68] ----
#pragma unroll
        for (int i = 0; i < 4; ++i) {
            float4 s4;
            s4.x = acc[i][0]; s4.y = acc[i][1]; s4.z = acc[i][2]; s4.w = acc[i][3];
            *reinterpret_cast<float4*>(&Blds[(ty * 4 + i) * 68 + tx * 4]) = s4;
        }
        __syncthreads();

        // ---- scan: running top-8 per (query, slice) in registers ----
        {
            int skb = sp * 256 + ck * 64 + vsl * 16;       // within-batch key
            const float* srow = &Blds[scanq * 68 + vsl * 16];
            const float* amp  = am + b * TT + skb;
#pragma unroll
            for (int w = 0; w < 4; ++w) {
                float4 d4 = *reinterpret_cast<const float4*>(srow + w * 4);
                float4 a4 = *reinterpret_cast<const float4*>(amp + w * 4);
                int s = skb + w * 4;
                float val;
                val = (mq * a4.x == 0.f) ? mneg : d4.x * sgq;
                if (val > tv[TK-1]) topk8_insert_strict(tv, tix, val, s + 0);
                val = (mq * a4.y == 0.f) ? mneg : d4.y * sgq;
                if (val > tv[TK-1]) topk8_insert_strict(tv, tix, val, s + 1);
                val = (mq * a4.z == 0.f) ? mneg : d4.z * sgq;
                if (val > tv[TK-1]) topk8_insert_strict(tv, tix, val, s + 2);
                val = (mq * a4.w == 0.f) ? mneg : d4.w * sgq;
                if (val > tv[TK-1]) topk8_insert_strict(tv, tix, val, s + 3);
            }
        }
        __syncthreads();   // all scan reads of Blds done

        if (ck < 3) {
            // write staged B regs into Blds
#pragma unroll
            for (int pass = 0; pass < 8; ++pass) {
                int sl = rr0 + pass * 8;
                int col = (((sl >> 2) ^ (c4 & 15)) << 2) + (sl & 3);
                Blds[(c4 * 4 + 0) * 64 + col] = breg[pass].x;
                Blds[(c4 * 4 + 1) * 64 + col] = breg[pass].y;
                Blds[(c4 * 4 + 2) * 64 + col] = breg[pass].z;
                Blds[(c4 * 4 + 3) * 64 + col] = breg[pass].w;
            }
            __syncthreads();
        }
    }

    // ---- merge the 4 slices per query, emit partial list for this split ----
    float* mv = Alds;                        // 2048 floats
    int*   mi = (int*)(Alds + 2048);
#pragma unroll
    for (int j = 0; j < TK; ++j) { mv[tid * 8 + j] = tv[j]; mi[tid * 8 + j] = tix[j]; }
    __syncthreads();
    if ((tid & 3) == 0) {
        for (int u = 1; u < 4; ++u) {
#pragma unroll
            for (int j = 0; j < TK; ++j) {
                float val = mv[(tid + u) * 8 + j];
                int   s   = mi[(tid + u) * 8 + j];
                if (val > tv[TK-1] || (val == tv[TK-1] && s < tix[TK-1]))
                    topk8_insert(tv, tix, val, s);
            }
        }
        int base = ((t0 + scanq) * NCH + sp) * TK;
#pragma unroll
        for (int j = 0; j < TK; ++j) { pv[base + j] = tv[j]; pi[base + j] = tix[j]; }
    }
}

// ---------------------------------------------------------------------------
// K3: per query, rescore ALL 128 candidates in f64 (exact ranking: f32*f32
// products are exact in f64, chain error ~1e-14), pick top-8 tie-aware,
// write idx (as float) + values, and gather x rows. Block per query.
// ---------------------------------------------------------------------------
__global__ __launch_bounds__(256) void merge_gather_kernel(
    const float* __restrict__ x,  const float* __restrict__ qm,
    const float* __restrict__ kmat, const float* __restrict__ gates,
    const float* __restrict__ am, const int* __restrict__ pi,
    float* __restrict__ out_g, float* __restrict__ out_i,
    float* __restrict__ out_v)
{
    int t = blockIdx.x;
    int b = t >> 12;

    __shared__ float  qrow[CQ];
    __shared__ double sval[NCH * TK];
    __shared__ int    scand[NCH * TK];
    __shared__ int    fidx[TK];

    if (threadIdx.x < 32) {
        *reinterpret_cast<float4*>(qrow + threadIdx.x * 4) =
            *reinterpret_cast<const float4*>(qm + (size_t)t * CQ + threadIdx.x * 4);
    }
    __syncthreads();

    if (threadIdx.x < NCH * TK) {
        int s = pi[(size_t)t * NCH * TK + threadIdx.x];
        const float* kr = kmat + (size_t)(b * TT + s) * CQ;
        double acc = 0.0;
#pragma unroll
        for (int d = 0; d < CQ; d += 4) {
            acc += (double)qrow[d + 0] * (double)kr[d + 0];
            acc += (double)qrow[d + 1] * (double)kr[d + 1];
            acc += (double)qrow[d + 2] * (double)kr[d + 2];
            acc += (double)qrow[d + 3] * (double)kr[d + 3];
        }
        double val;
        float ms  = am[b * TT + s];
        float mqq = am[t];
        if (mqq * ms == 0.f) val = -1e9;
        else                 val = acc * 0.08838834764831845;
        val *= (double)gates[t];
        sval[threadIdx.x]  = val;
        scand[threadIdx.x] = s;
    }
    __syncthreads();

    if (threadIdx.x == 0) {
        double v[TK]; int ix[TK];
#pragma unroll
        for (int j = 0; j < TK; ++j) { v[j] = -1.0e300; ix[j] = 0x7FFFFFFF; }
        for (int c = 0; c < NCH * TK; ++c) {
            double val = sval[c]; int s = scand[c];
            if (val > v[TK-1] || (val == v[TK-1] && s < ix[TK-1]))
                topk8d_insert(v, ix, val, s);
        }
#pragma unroll
        for (int j = 0; j < TK; ++j) {
            out_i[t * TK + j] = (float)ix[j];
            out_v[t * TK + j] = (float)v[j];
            fidx[j] = ix[j];
        }
    }
    __syncthreads();

#pragma unroll
    for (int j = 0; j < TK; ++j) {
        int row = fidx[j];
        float4 val4 = *reinterpret_cast<const float4*>(
            x + ((size_t)(b * TT + row)) * DD + threadIdx.x * 4);
        *reinterpret_cast<float4*>(
            out_g + ((size_t)(t * TK + j)) * DD + threadIdx.x * 4) = val4;
    }
}

// ---------------------------------------------------------------------------
extern "C" void kernel_launch(void* const* d_in, const int* in_sizes, int n_in,
                              void* d_out, int out_size, void* d_ws, size_t ws_size,
                              hipStream_t stream) {
    const float* x  = (const float*)d_in[0];
    const float* am = (const float*)d_in[1];
    const float* Wq = (const float*)d_in[2];
    const float* bq = (const float*)d_in[3];
    const float* Wk = (const float*)d_in[4];
    const float* bk = (const float*)d_in[5];
    const float* Wg = (const float*)d_in[6];
    const float* bg = (const float*)d_in[7];

    float* ws = (float*)d_ws;
    float* q  = ws;                              // NT*CQ      = 1048576
    float* k  = ws + 1048576;                    // NT*CQ      = 1048576
    float* g  = ws + 2097152;                    // NT         = 8192
    float* pv = ws + 2105344;                    // NT*NCH*TK  = 1048576
    int*   pi = (int*)(ws + 3153920);            // NT*NCH*TK  = 1048576

    float* out_g = (float*)d_out;                // [B,T,K,D] = 67108864
    float* out_i = out_g + 67108864;             // [B,T,K]   = 65536 (as float)
    float* out_v = out_i + 65536;                // [B,T,K]   = 65536

    proj_kernel<<<dim3(NT / 256, 16), 256, 0, stream>>>(x, Wq, bq, Wk, bk, q, k);
    gate_kernel<<<NT / 4, 256, 0, stream>>>(x, Wg, bg, g);
    simtopk_kernel<<<dim3(128, NCH), 256, 0, stream>>>(q, k, g, am, pv, pi);
    merge_gather_kernel<<<NT, 256, 0, stream>>>(x, q, k, g, am, pi,
                                                out_g, out_i, out_v);
}